// Round 1
// baseline (22669.273 us; speedup 1.0000x reference)
//
#include <hip/hip_runtime.h>

// LSTM autoregressive forward, MI355X persistent-block design.
// B=512 independent recurrences -> 256 blocks x 512 threads (8 waves, 1 block/CU),
// 2 batch rows per block. Weights live in VGPRs:
//   thread t: W_ih row t (64 f32) + W_hh row t (128 f32) + W_den quarter (32 f32).
// Activations broadcast via LDS. No grid sync anywhere.

#define T_SEQ 1024
#define N_F   64
#define N_H   128
#define NG    512   // 4*N_H

__device__ __forceinline__ float sigf(float x) {
    // 1/(1+e^-x); rcp(inf)=0 handles saturation cleanly
    return __builtin_amdgcn_rcpf(1.f + __expf(-x));
}
__device__ __forceinline__ float tanh_fast(float x) {
    // tanh(x) = 1 - 2/(1+e^{2x}); exact at +-inf via rcp(inf)=0
    return 1.f - 2.f * __builtin_amdgcn_rcpf(1.f + __expf(2.f * x));
}

__global__ __launch_bounds__(512, 2)
void lstm_autoreg(const float* __restrict__ x,
                  const int*   __restrict__ avail,
                  const int*   __restrict__ pred,
                  const float* __restrict__ W_ih,
                  const float* __restrict__ W_hh,
                  const float* __restrict__ b_ih,
                  const float* __restrict__ b_hh,
                  const float* __restrict__ W_den,
                  const float* __restrict__ b_den,
                  const float* __restrict__ init_ch,
                  float*       __restrict__ out)
{
    // stride 68 floats = 272B: 16B-aligned rows AND breaks the f-major bank collision
    __shared__ __align__(16) float xchunk[2][N_F][68];
    __shared__ __align__(16) float xin[2][N_F];
    __shared__ __align__(16) float hbuf[2][N_H];
    __shared__ __align__(16) float gbuf[NG][2];   // [gate][row] interleaved
    __shared__ __align__(16) float prevout[2][N_F];
    __shared__ int red[8];

    const int tid = threadIdx.x;
    const int r0  = blockIdx.x * 2;

    // ---- max_idx = min(max(predict_len), T) : block-local reduction (512 = batch) ----
    int pv = pred[tid];
    #pragma unroll
    for (int m = 1; m < 64; m <<= 1) pv = max(pv, __shfl_xor(pv, m));
    if ((tid & 63) == 0) red[tid >> 6] = pv;
    __syncthreads();
    int max_idx = red[0];
    #pragma unroll
    for (int w = 1; w < 8; ++w) max_idx = max(max_idx, red[w]);
    if (max_idx > T_SEQ) max_idx = T_SEQ;

    // ---- weights into registers ----
    float4 wih4[16], whh4[32], wden4[8];
    {
        const float4* p = (const float4*)(W_ih + tid * N_F);
        #pragma unroll
        for (int i = 0; i < 16; ++i) wih4[i] = p[i];
        const float4* q = (const float4*)(W_hh + tid * N_H);
        #pragma unroll
        for (int i = 0; i < 32; ++i) whh4[i] = q[i];
    }
    const int of   = (tid >> 2) & 63;  // dense-out feature
    const int oq   = tid & 3;          // quarter of the K=128 reduction
    const int orow = tid >> 8;         // batch row for dense-out
    {
        const float4* p = (const float4*)(W_den + of * N_H + oq * 32);
        #pragma unroll
        for (int i = 0; i < 8; ++i) wden4[i] = p[i];
    }
    const float bacc = b_ih[tid] + b_hh[tid];
    const float bden = b_den[of];

    const int a0 = avail[r0], a1 = avail[r0 + 1];
    const int p0 = pred[r0],  p1 = pred[r0 + 1];

    // ---- state init ----
    float c = 0.f;
    if (tid < 256) {
        int row = tid >> 7, j = tid & 127;
        c = init_ch[j];                   // c0 = init_ch[:H]
        hbuf[row][j] = init_ch[N_H + j];  // h0 = init_ch[H:]
    }
    if (tid < 128) {
        int row = tid >> 6, f = tid & 63;
        prevout[row][f] = 0.f;            // never used at t=0 (fb requires t>0)
    }
    const int obase = ((r0 + orow) * N_F + of) * T_SEQ;

    for (int t = 0; t < T_SEQ; ++t) {
        // ---- stage next 64 timesteps of x into LDS (coalesced) ----
        if ((t & 63) == 0) {
            #pragma unroll
            for (int it = 0; it < 4; ++it) {
                int idx = tid + it * 512;        // 2048 float4 total
                int tq  = idx & 15;
                int f   = (idx >> 4) & 63;
                int row = idx >> 10;
                const float4* src =
                    (const float4*)(x + ((r0 + row) * N_F + f) * T_SEQ + t) + tq;
                *(float4*)&xchunk[row][f][tq * 4] = *src;
            }
            __syncthreads();
        }

        // ---- x_in select (feedback vs input) ----
        if (tid < 128) {
            int row = tid >> 6, f = tid & 63;
            int av = row ? a1 : a0, pr = row ? p1 : p0;
            bool fb = (t >= av) && (t < pr) && (t > 0);
            xin[row][f] = fb ? prevout[row][f] : xchunk[row][f][t & 63];
        }
        __syncthreads();

        // ---- gate dot products: thread = one gate row, both batch rows ----
        float acc0 = bacc, acc1 = bacc;
        {
            const float4* x0 = (const float4*)xin[0];
            const float4* x1 = (const float4*)xin[1];
            #pragma unroll
            for (int i = 0; i < 16; ++i) {
                float4 w = wih4[i]; float4 u = x0[i]; float4 v = x1[i];
                acc0 = fmaf(w.x, u.x, acc0); acc0 = fmaf(w.y, u.y, acc0);
                acc0 = fmaf(w.z, u.z, acc0); acc0 = fmaf(w.w, u.w, acc0);
                acc1 = fmaf(w.x, v.x, acc1); acc1 = fmaf(w.y, v.y, acc1);
                acc1 = fmaf(w.z, v.z, acc1); acc1 = fmaf(w.w, v.w, acc1);
            }
            const float4* h0 = (const float4*)hbuf[0];
            const float4* h1 = (const float4*)hbuf[1];
            #pragma unroll
            for (int i = 0; i < 32; ++i) {
                float4 w = whh4[i]; float4 u = h0[i]; float4 v = h1[i];
                acc0 = fmaf(w.x, u.x, acc0); acc0 = fmaf(w.y, u.y, acc0);
                acc0 = fmaf(w.z, u.z, acc0); acc0 = fmaf(w.w, u.w, acc0);
                acc1 = fmaf(w.x, v.x, acc1); acc1 = fmaf(w.y, v.y, acc1);
                acc1 = fmaf(w.z, v.z, acc1); acc1 = fmaf(w.w, v.w, acc1);
            }
        }
        gbuf[tid][0] = acc0;
        gbuf[tid][1] = acc1;
        __syncthreads();

        // ---- elementwise LSTM cell (256 threads = 2 rows x 128 hid) ----
        if (tid < 256) {
            int row = tid >> 7, j = tid & 127;
            float gi = gbuf[j][row];
            float gf = gbuf[N_H + j][row];
            float gg = gbuf[2 * N_H + j][row];
            float go = gbuf[3 * N_H + j][row];
            c = sigf(gf) * c + sigf(gi) * tanh_fast(gg);
            float h = sigf(go) * tanh_fast(c);
            hbuf[row][j] = h;
        }
        __syncthreads();

        // ---- dense out: 512 quarter-dots, quad shuffle-reduce ----
        {
            float d = 0.f;
            const float4* hq = (const float4*)&hbuf[orow][oq * 32];
            #pragma unroll
            for (int i = 0; i < 8; ++i) {
                float4 w = wden4[i]; float4 h4 = hq[i];
                d = fmaf(w.x, h4.x, d); d = fmaf(w.y, h4.y, d);
                d = fmaf(w.z, h4.z, d); d = fmaf(w.w, h4.w, d);
            }
            d += __shfl_xor(d, 1);
            d += __shfl_xor(d, 2);
            if (oq == 0) {
                float o = d + bden;
                prevout[orow][of] = o;                    // unmasked feedback
                out[obase + t] = (t < max_idx) ? o : 0.f; // masked store
            }
        }
        __syncthreads();
    }
}

extern "C" void kernel_launch(void* const* d_in, const int* in_sizes, int n_in,
                              void* d_out, int out_size, void* d_ws, size_t ws_size,
                              hipStream_t stream) {
    const float* x      = (const float*)d_in[0];
    const int*   avail  = (const int*)  d_in[1];
    const int*   pred   = (const int*)  d_in[2];
    const float* W_ih   = (const float*)d_in[3];
    const float* W_hh   = (const float*)d_in[4];
    const float* b_ih   = (const float*)d_in[5];
    const float* b_hh   = (const float*)d_in[6];
    const float* W_den  = (const float*)d_in[7];
    const float* b_den  = (const float*)d_in[8];
    const float* initch = (const float*)d_in[9];
    float* out = (float*)d_out;

    hipLaunchKernelGGL(lstm_autoreg, dim3(256), dim3(512), 0, stream,
                       x, avail, pred, W_ih, W_hh, b_ih, b_hh, W_den, b_den,
                       initch, out);
}

// Round 3
// 2059.656 us; speedup vs baseline: 11.0063x; 11.0063x over previous
//
#include <hip/hip_runtime.h>
#include <cstdint>

// Autoregressive LSTM, MI355X. 256 blocks x 512 threads (1 block/CU, 2 waves/SIMD),
// 2 batch rows per block. All weights live in VGPRs as PACKED f16 pairs, consumed
// with v_dot2_f32_f16 (f32 accumulate). Gate rows remapped so the 4 gates of hidden
// unit j sit in one lane-quad -> cell update via quad shuffles, no gate LDS buffer.
// 2 barriers per timestep. Outputs staged in LDS, flushed coalesced every 32 steps.

#define T_SEQ 1024
#define N_F   64
#define N_H   128

typedef _Float16 h2f __attribute__((ext_vector_type(2)));

__device__ __forceinline__ float sigf(float x) {
    return __builtin_amdgcn_rcpf(1.f + __expf(-x));
}
__device__ __forceinline__ float tanh_fast(float x) {
    return 1.f - 2.f * __builtin_amdgcn_rcpf(1.f + __expf(2.f * x));
}

#if __has_builtin(__builtin_amdgcn_fdot2)
__device__ __forceinline__ float fdot2(uint32_t a, uint32_t b, float c) {
    return __builtin_amdgcn_fdot2(__builtin_bit_cast(h2f, a),
                                  __builtin_bit_cast(h2f, b), c, false);
}
#else
__device__ __forceinline__ float fdot2(uint32_t a, uint32_t b, float c) {
    h2f av = __builtin_bit_cast(h2f, a), bv = __builtin_bit_cast(h2f, b);
    return fmaf((float)av.x, (float)bv.x, fmaf((float)av.y, (float)bv.y, c));
}
#endif

__device__ __forceinline__ uint32_t packh2(float a, float b) {
    h2f v; v.x = (_Float16)a; v.y = (_Float16)b;
    return __builtin_bit_cast(uint32_t, v);
}

__global__ __launch_bounds__(512, 2)
void lstm_autoreg(const float* __restrict__ x,
                  const int*   __restrict__ avail,
                  const int*   __restrict__ pred,
                  const float* __restrict__ W_ih,
                  const float* __restrict__ W_hh,
                  const float* __restrict__ b_ih,
                  const float* __restrict__ b_hh,
                  const float* __restrict__ W_den,
                  const float* __restrict__ b_den,
                  const float* __restrict__ init_ch,
                  float*       __restrict__ out)
{
    __shared__ __align__(16) uint32_t xT[2][64][32];    // [row][tmod][fpair] f16x2, 16KB
    __shared__ __align__(16) float    obuf[2][N_F][36]; // out staging, 18KB
    __shared__ __align__(16) uint32_t h2buf[2][2][64];  // [buf][row][jpair] f16x2
    __shared__ __align__(16) uint32_t pv2[2][32];       // prev out f16 [row][fpair]
    __shared__ int red[8];

    const int tid  = threadIdx.x;
    const int lane = tid & 63;
    const int r0   = blockIdx.x * 2;

    // ---- max_idx = min(max(predict_len), T) ----
    int pv = pred[tid];
    #pragma unroll
    for (int m = 1; m < 64; m <<= 1) pv = max(pv, __shfl_xor(pv, m));
    if (lane == 0) red[tid >> 6] = pv;
    __syncthreads();
    int max_idx = red[0];
    #pragma unroll
    for (int w = 1; w < 8; ++w) max_idx = max(max_idx, red[w]);
    if (max_idx > T_SEQ) max_idx = T_SEQ;

    // ---- role indices ----
    const int gt = tid & 3;          // gate type (i,f,g,o)
    const int j  = tid >> 2;         // hidden unit [0,128)
    const int g  = gt * N_H + j;     // weight row
    const int of = tid >> 3;         // dense feature [0,64)
    const int oc = tid & 7;          // dense K-chunk [0,8)

    // ---- weights -> packed f16 in VGPRs ----
    uint32_t wih[32], whh[64], wdn[8];
    {
        const float* p = W_ih + g * N_F;
        #pragma unroll
        for (int i = 0; i < 32; ++i) wih[i] = packh2(p[2*i], p[2*i+1]);
        const float* q = W_hh + g * N_H;
        #pragma unroll
        for (int i = 0; i < 64; ++i) whh[i] = packh2(q[2*i], q[2*i+1]);
        const float* r = W_den + of * N_H + oc * 16;
        #pragma unroll
        for (int i = 0; i < 8; ++i) wdn[i] = packh2(r[2*i], r[2*i+1]);
    }
    // pin: block rematerialization of the weight loads
    #pragma unroll
    for (int i = 0; i < 32; ++i) asm volatile("" : "+v"(wih[i]));
    #pragma unroll
    for (int i = 0; i < 64; ++i) asm volatile("" : "+v"(whh[i]));
    #pragma unroll
    for (int i = 0; i < 8; ++i)  asm volatile("" : "+v"(wdn[i]));

    const float bacc = b_ih[g] + b_hh[g];
    const float bden = b_den[of];
    const int a0 = avail[r0], a1 = avail[r0 + 1];
    const int p0 = pred[r0],  p1 = pred[r0 + 1];

    // ---- state init ----
    float c0 = init_ch[j], c1 = init_ch[j];          // c0 = init_ch[:H]
    if (tid < 64) {
        uint32_t hp = packh2(init_ch[N_H + 2*tid], init_ch[N_H + 2*tid + 1]);
        h2buf[0][0][tid] = hp;
        h2buf[0][1][tid] = hp;
    }
    __syncthreads();

    for (int t = 0; t < T_SEQ; ++t) {
        // ---- stage 64 timesteps of x, transposed, f32 -> f16 ----
        if ((t & 63) == 0) {
            #pragma unroll
            for (int k = 0; k < 4; ++k) {
                int idx = tid + k * 512;            // 2048 float4
                int tq = idx & 15, f = (idx >> 4) & 63, row = idx >> 10;
                const float4 v = *(const float4*)
                    (x + ((size_t)(r0 + row) * N_F + f) * T_SEQ + t + tq * 4);
                _Float16* dst = (_Float16*)&xT[row][0][0];
                dst[(tq*4+0)*64 + f] = (_Float16)v.x;
                dst[(tq*4+1)*64 + f] = (_Float16)v.y;
                dst[(tq*4+2)*64 + f] = (_Float16)v.z;
                dst[(tq*4+3)*64 + f] = (_Float16)v.w;
            }
            __syncthreads();
        }
        const int rb = t & 1, wb = rb ^ 1;
        const int tm = t & 63;

        // ---- phase A: gates + cell ----
        const bool fb0 = (t >= a0) & (t < p0) & (t > 0);
        const bool fb1 = (t >= a1) & (t < p1) & (t > 0);
        const uint32_t* xs0 = fb0 ? pv2[0] : &xT[0][tm][0];
        const uint32_t* xs1 = fb1 ? pv2[1] : &xT[1][tm][0];
        const uint32_t* h0  = h2buf[rb][0];
        const uint32_t* h1  = h2buf[rb][1];

        float A0 = bacc, A1 = bacc, B0 = 0.f, B1 = 0.f;
        #pragma unroll
        for (int i = 0; i < 32; ++i) {
            A0 = fdot2(wih[i], xs0[i], A0);
            A1 = fdot2(wih[i], xs1[i], A1);
        }
        #pragma unroll
        for (int i = 0; i < 64; ++i) {
            B0 = fdot2(whh[i], h0[i], B0);
            B1 = fdot2(whh[i], h1[i], B1);
        }
        float g0 = A0 + B0, g1 = A1 + B1;

        // quad exchange: lanes (qb..qb+3) hold gates i,f,g,o of hidden j
        const int qb = lane & ~3;
        float gi0 = __shfl(g0, qb+0), gf0 = __shfl(g0, qb+1);
        float gg0 = __shfl(g0, qb+2), go0 = __shfl(g0, qb+3);
        float gi1 = __shfl(g1, qb+0), gf1 = __shfl(g1, qb+1);
        float gg1 = __shfl(g1, qb+2), go1 = __shfl(g1, qb+3);

        c0 = sigf(gf0) * c0 + sigf(gi0) * tanh_fast(gg0);
        c1 = sigf(gf1) * c1 + sigf(gi1) * tanh_fast(gg1);
        float h0v = sigf(go0) * tanh_fast(c0);
        float h1v = sigf(go1) * tanh_fast(c1);
        if (gt == 0) {
            _Float16* hp = (_Float16*)&h2buf[wb][0][0];
            hp[j]        = (_Float16)h0v;
            hp[128 + j]  = (_Float16)h1v;
        }
        __syncthreads();

        // ---- phase B: dense out ----
        const uint32_t* hq0 = &h2buf[wb][0][oc * 8];
        const uint32_t* hq1 = &h2buf[wb][1][oc * 8];
        float d0 = 0.f, d1 = 0.f;
        #pragma unroll
        for (int i = 0; i < 8; ++i) {
            d0 = fdot2(wdn[i], hq0[i], d0);
            d1 = fdot2(wdn[i], hq1[i], d1);
        }
        d0 += __shfl_xor(d0, 1); d0 += __shfl_xor(d0, 2); d0 += __shfl_xor(d0, 4);
        d1 += __shfl_xor(d1, 1); d1 += __shfl_xor(d1, 2); d1 += __shfl_xor(d1, 4);
        if (oc == 0) {
            float o0 = d0 + bden, o1 = d1 + bden;
            _Float16* pp = (_Float16*)&pv2[0][0];
            pp[of]      = (_Float16)o0;          // feedback (unmasked)
            pp[64 + of] = (_Float16)o1;
            obuf[0][of][t & 31] = (t < max_idx) ? o0 : 0.f;
            obuf[1][of][t & 31] = (t < max_idx) ? o1 : 0.f;
        }

        // ---- flush outputs, coalesced, every 32 steps ----
        if ((t & 31) == 31) {
            __syncthreads();
            const int tb = t & ~31;
            #pragma unroll
            for (int k = 0; k < 2; ++k) {
                int idx = tid + k * 512;          // 1024 float4
                int row = idx >> 9, f = (idx >> 3) & 63, tq = idx & 7;
                float4 v = *(const float4*)&obuf[row][f][tq * 4];
                *(float4*)(out + ((size_t)(r0 + row) * N_F + f) * T_SEQ + tb + tq * 4) = v;
            }
        }
        __syncthreads();
    }
}

extern "C" void kernel_launch(void* const* d_in, const int* in_sizes, int n_in,
                              void* d_out, int out_size, void* d_ws, size_t ws_size,
                              hipStream_t stream) {
    const float* x      = (const float*)d_in[0];
    const int*   avail  = (const int*)  d_in[1];
    const int*   pred   = (const int*)  d_in[2];
    const float* W_ih   = (const float*)d_in[3];
    const float* W_hh   = (const float*)d_in[4];
    const float* b_ih   = (const float*)d_in[5];
    const float* b_hh   = (const float*)d_in[6];
    const float* W_den  = (const float*)d_in[7];
    const float* b_den  = (const float*)d_in[8];
    const float* initch = (const float*)d_in[9];
    float* out = (float*)d_out;

    hipLaunchKernelGGL(lstm_autoreg, dim3(256), dim3(512), 0, stream,
                       x, avail, pred, W_ih, W_hh, b_ih, b_hh, W_den, b_den,
                       initch, out);
}